// Round 19
// baseline (42.914 us; speedup 1.0000x reference)
//
#include <hip/hip_runtime.h>
#include <hip/hip_fp16.h>

typedef __attribute__((ext_vector_type(4))) float f32x4;

#define NROWS 8192
#define DCOLS 256
#define MARGIN 0.5f
#define NT 64          // 8192/128 tiles per dim
#define NBLK 2080      // NT*(NT+1)/2 upper-triangle tiles

// --- Kernel 1: L2-normalize rows fp32 -> fp8 e5m2 (= truncated fp16), row-major.
__global__ __launch_bounds__(256) void norm_kernel(const float* __restrict__ x,
                                                   unsigned char* __restrict__ e) {
    const int t = threadIdx.x;
    const int l = t & 63;
    const int c = l & 31;
    const int row = blockIdx.x * 8 + (t >> 6) * 2 + (l >> 5);

    const float4 v0 = *reinterpret_cast<const float4*>(&x[row * DCOLS + c * 8]);
    const float4 v1 = *reinterpret_cast<const float4*>(&x[row * DCOLS + c * 8 + 4]);
    float ss = v0.x * v0.x + v0.y * v0.y + v0.z * v0.z + v0.w * v0.w
             + v1.x * v1.x + v1.y * v1.y + v1.z * v1.z + v1.w * v1.w;
#pragma unroll
    for (int off = 16; off >= 1; off >>= 1) ss += __shfl_xor(ss, off, 32);
    const float inv = 1.0f / fmaxf(sqrtf(ss), 1e-12f);

    const float f[8] = {v0.x, v0.y, v0.z, v0.w, v1.x, v1.y, v1.z, v1.w};
    unsigned int lo = 0, hi = 0;
#pragma unroll
    for (int i = 0; i < 4; ++i) {
        const unsigned short hb = __half_as_ushort(__float2half(f[i] * inv));
        lo |= (unsigned int)(hb >> 8) << (8 * i);           // e5m2 = fp16 top byte
    }
#pragma unroll
    for (int i = 0; i < 4; ++i) {
        const unsigned short hb = __half_as_ushort(__float2half(f[4 + i] * inv));
        hi |= (unsigned int)(hb >> 8) << (8 * i);
    }
    uint2 o; o.x = lo; o.y = hi;
    *reinterpret_cast<uint2*>(e + (size_t)row * DCOLS + c * 8) = o;
}

// --- Kernel 2: MAX-OCCUPANCY tile kernel (R19). One 128x128 tile per block.
// 1024 thr = 16 waves (4M x 4N), wave tile 32x32: acc[2][2] of 16x16x32
// bf8_bf8 (2-VGPR fragments) -> ~50 VGPR/wave; __launch_bounds__(1024,8)
// caps at 64 VGPR = 8 waves/SIMD (VGPR pool 512/SIMD, m69). MFMA issue rate
// saturates only near 8 waves/SIMD (P1: 28 cyc/MFMA at 2.1 waves/SIMD) --
// occupancy IS the lever. A+B staged full-K once (64 KB, conflict-free
// k-major layout), ONE barrier; compute loop is pure {ds_read x4, MFMA x4}
// x8 with no waits (compiler pipelines, m97). 2 blocks/CU.
__global__ __launch_bounds__(1024, 8) void tile_kernel(const unsigned char* __restrict__ e,
                                                       float* __restrict__ part) {
    // XCD-aware bijective swizzle (NBLK = 2080 = 8*260)
    const int orig = blockIdx.x;
    const int t0 = (orig & 7) * 260 + (orig >> 3);
    // decode t0 -> (bi,bj), bi<=bj; row bi holds 64-bi tiles. CUM(b)=b*(129-b)/2
    int bi = (int)((129.0 - sqrt(16641.0 - 8.0 * (double)t0)) * 0.5);
    if (bi < 0) bi = 0;
    if (bi > NT - 1) bi = NT - 1;
#define CUM(b) (((b) * (129 - (b))) >> 1)
    while (bi + 1 <= NT - 1 && CUM(bi + 1) <= t0) ++bi;
    while (bi > 0 && CUM(bi) > t0) --bi;
    const int bj = bi + (t0 - CUM(bi));
#undef CUM

    __shared__ char As[32768];   // [kt 0..7][kh 0..1][row 0..127][16B]
    __shared__ char Bs[32768];   // same layout
    __shared__ float red[16];

    const int t = threadIdx.x;
    const int l = t & 63;
    const int w = t >> 6;        // 0..15
    const int wm = w >> 2;       // 0..3: rows wm*32
    const int wn = w & 3;        // 0..3: cols wn*32
    const int lr = l & 15;
    const int hk = l >> 4;

    const unsigned char* eA = e + (size_t)bi * 128 * DCOLS;
    const unsigned char* eB = e + (size_t)bj * 128 * DCOLS;

    // --- stage A+B full K (2+2 chunks/thread, 16B each, linear LDS dest;
    // conflict-free k-major: chunk (kt,kh,row) <- global row*DCOLS+kt*32+kh*16 ---
#pragma unroll
    for (int i = 0; i < 2; ++i) {
        const int u = i * 1024 + t;           // 0..2047
        const int kt = u >> 8, kh = (u >> 7) & 1, row = u & 127;
        __builtin_amdgcn_global_load_lds(
            (const __attribute__((address_space(1))) void*)(eA + row * DCOLS + kt * 32 + kh * 16),
            (__attribute__((address_space(3))) void*)(As + u * 16), 16, 0, 0);
    }
#pragma unroll
    for (int i = 0; i < 2; ++i) {
        const int u = i * 1024 + t;
        const int kt = u >> 8, kh = (u >> 7) & 1, row = u & 127;
        __builtin_amdgcn_global_load_lds(
            (const __attribute__((address_space(1))) void*)(eB + row * DCOLS + kt * 32 + kh * 16),
            (__attribute__((address_space(3))) void*)(Bs + u * 16), 16, 0, 0);
    }
    asm volatile("s_waitcnt vmcnt(0)" ::: "memory");
    __builtin_amdgcn_s_barrier();
    __builtin_amdgcn_sched_barrier(0);

    // lane read offset within a kt region: kh-half (hk>>1), row lr, byte8 (hk&1)
    // 16-lane phase (fixed hk): addr stride 16B -> 8 banks x 2 lanes = free.
    const int ro = (hk >> 1) * 2048 + lr * 16 + (hk & 1) * 8;

    f32x4 acc[2][2];
#pragma unroll
    for (int m = 0; m < 2; ++m)
#pragma unroll
        for (int n = 0; n < 2; ++n)
            acc[m][n] = (f32x4){0.f, 0.f, 0.f, 0.f};

    // --- compute: 8 K-steps, no in-loop sync (compiler software-pipelines) ---
#pragma unroll
    for (int kt = 0; kt < 8; ++kt) {
        long af[2], bf[2];
#pragma unroll
        for (int m = 0; m < 2; ++m)
            af[m] = *reinterpret_cast<const long*>(
                As + kt * 4096 + (wm * 32 + m * 16) * 16 + ro);
#pragma unroll
        for (int n = 0; n < 2; ++n)
            bf[n] = *reinterpret_cast<const long*>(
                Bs + kt * 4096 + (wn * 32 + n * 16) * 16 + ro);
#pragma unroll
        for (int m = 0; m < 2; ++m)
#pragma unroll
            for (int n = 0; n < 2; ++n)
                acc[m][n] = __builtin_amdgcn_mfma_f32_16x16x32_bf8_bf8(
                    af[m], bf[n], acc[m][n], 0, 0, 0);
    }

    // --- epilogue: relu(sim - margin), strict upper-triangle mask, reduce ---
    // C/D layout (m89-verified, dtype-independent): col=lane&15, row=(lane>>4)*4+reg.
    const int gi0 = bi * 128 + wm * 32;
    const int gj0 = bj * 128 + wn * 32;
    float local = 0.0f;
    if (bi == bj) {
#pragma unroll
        for (int m = 0; m < 2; ++m)
#pragma unroll
            for (int n = 0; n < 2; ++n)
#pragma unroll
                for (int r = 0; r < 4; ++r) {
                    const int gi = gi0 + m * 16 + hk * 4 + r;
                    const int gj = gj0 + n * 16 + lr;
                    local += (gi < gj) ? fmaxf(acc[m][n][r] - MARGIN, 0.0f) : 0.0f;
                }
    } else {   // bj > bi: all pairs strictly upper-triangular
#pragma unroll
        for (int m = 0; m < 2; ++m)
#pragma unroll
            for (int n = 0; n < 2; ++n)
#pragma unroll
                for (int r = 0; r < 4; ++r)
                    local += fmaxf(acc[m][n][r] - MARGIN, 0.0f);
    }

    // --- block reduction (16 waves) -> one partial, no atomics ---
#pragma unroll
    for (int off = 32; off >= 1; off >>= 1) local += __shfl_down(local, off);
    if (l == 0) red[w] = local;
    __syncthreads();
    if (t == 0) {
        float s = 0.0f;
#pragma unroll
        for (int i = 0; i < 16; ++i) s += red[i];
        part[orig] = s;
    }
}

// --- Kernel 3: reduce NBLK partials, finalize ---
__global__ __launch_bounds__(1024) void fin_kernel(const float* __restrict__ part,
                                                   float* __restrict__ out) {
    __shared__ float red[16];
    const int t = threadIdx.x;
    float v = part[t] + part[t + 1024] + (t < NBLK - 2048 ? part[t + 2048] : 0.0f);
#pragma unroll
    for (int off = 32; off >= 1; off >>= 1) v += __shfl_down(v, off);
    if ((t & 63) == 0) red[t >> 6] = v;
    __syncthreads();
    if (t == 0) {
        float s = 0.0f;
#pragma unroll
        for (int i = 0; i < 16; ++i) s += red[i];
        out[0] = s / 33550336.0f;   // n*(n-1)/2 for n=8192
    }
}

extern "C" void kernel_launch(void* const* d_in, const int* in_sizes, int n_in,
                              void* d_out, int out_size, void* d_ws, size_t ws_size,
                              hipStream_t stream) {
    const float* x = (const float*)d_in[0];
    float* out = (float*)d_out;
    unsigned char* e = (unsigned char*)d_ws;                        // 2 MB fp8
    float* part = (float*)((char*)d_ws + (size_t)NROWS * DCOLS);    // 2080 floats

    norm_kernel<<<NROWS / 8, 256, 0, stream>>>(x, e);
    tile_kernel<<<NBLK, 1024, 0, stream>>>(e, part);
    fin_kernel<<<1, 1024, 0, stream>>>(part, out);
}

// Round 20
// 33.003 us; speedup vs baseline: 1.3003x; 1.3003x over previous
//
#include <hip/hip_runtime.h>
#include <hip/hip_fp16.h>

typedef __attribute__((ext_vector_type(4))) float f32x4;
typedef __attribute__((ext_vector_type(8))) int i32x8;

#define NROWS 8192
#define DCOLS 256
#define MARGIN 0.5f
#define NBAND 128      // 64-row bands
#define NCT 64         // 128-col tiles
#define NBLOCKS 1088   // sum over bands of ceil((64 - band/2)/4)

// --- Kernel 1: L2-normalize rows fp32 -> fp8 e5m2 (= truncated fp16), row-major.
__global__ __launch_bounds__(256) void norm_kernel(const float* __restrict__ x,
                                                   unsigned char* __restrict__ e) {
    const int t = threadIdx.x;
    const int l = t & 63;
    const int c = l & 31;
    const int row = blockIdx.x * 8 + (t >> 6) * 2 + (l >> 5);

    const float4 v0 = *reinterpret_cast<const float4*>(&x[row * DCOLS + c * 8]);
    const float4 v1 = *reinterpret_cast<const float4*>(&x[row * DCOLS + c * 8 + 4]);
    float ss = v0.x * v0.x + v0.y * v0.y + v0.z * v0.z + v0.w * v0.w
             + v1.x * v1.x + v1.y * v1.y + v1.z * v1.z + v1.w * v1.w;
#pragma unroll
    for (int off = 16; off >= 1; off >>= 1) ss += __shfl_xor(ss, off, 32);
    const float inv = 1.0f / fmaxf(sqrtf(ss), 1e-12f);

    const float f[8] = {v0.x, v0.y, v0.z, v0.w, v1.x, v1.y, v1.z, v1.w};
    unsigned int lo = 0, hi = 0;
#pragma unroll
    for (int i = 0; i < 4; ++i) {
        const unsigned short hb = __half_as_ushort(__float2half(f[i] * inv));
        lo |= (unsigned int)(hb >> 8) << (8 * i);           // e5m2 = fp16 top byte
    }
#pragma unroll
    for (int i = 0; i < 4; ++i) {
        const unsigned short hb = __half_as_ushort(__float2half(f[4 + i] * inv));
        hi |= (unsigned int)(hb >> 8) << (8 * i);
    }
    uint2 o; o.x = lo; o.y = hi;
    *reinterpret_cast<uint2*>(e + (size_t)row * DCOLS + c * 8) = o;
}

// --- Kernel 2: MX-fp8 K=128, 64-row bands, 4 waves/SIMD (R20).
// Block = (band bi of 64 rows, run of <=4 col-tiles of 128). 256 thr = 4 waves,
// wave owns cols wn*32 of the tile: acc[4][2] of mfma_scale_f32_16x16x128
// (bf8/bf8, scale=1.0; call verified in-context R18). K=256 = 2 kb-blocks.
// A band hoisted to af[2][4] regs (64 VGPR) via an 8KB LDS bounce; B:
// wave-private 4KB ring-2 slices, own-vmcnt gates (vmcnt(4) = loads issued 2
// steps back), lgkmcnt(0) orders slot reuse. ~127 VGPR @ (256,4) -> 4 waves/
// SIMD; LDS 40KB -> 4 blocks/CU (160KB). No in-loop barriers.
__global__ __launch_bounds__(256, 4) void tile_kernel(const unsigned char* __restrict__ e,
                                                      float* __restrict__ part) {
    // XCD swizzle (1088 = 8*136), then band/run decode
    const int orig = blockIdx.x;
    int bb = (orig & 7) * 136 + (orig >> 3);
    int bi = 0, r;
    while (bb >= (r = ((NCT - (bi >> 1)) + 3) >> 2)) { bb -= r; ++bi; }
    const int j0 = (bi >> 1) + bb * 4;        // first col-tile of run
    const int nj = min(4, NCT - j0);
    const int NS = nj * 2;                    // (tile, kb) streams

    __shared__ char lds[40960];               // [0,8K): A bounce / red ; [8K,40K): B
    char* As = lds;
    char* Bw = lds + 8192;                    // 4 waves x 2 slots x 4KB

    const int t = threadIdx.x;
    const int l = t & 63;
    const int w = t >> 6;       // wave id: cols wn*32 of the tile
    const int wn = w;
    const int lr = l & 15;
    const int hk = l >> 4;
    const unsigned char* eA = e + (size_t)bi * 64 * DCOLS;
    char* myB = Bw + w * 8192;

    // stage one B stream (tile jt = j0+(s>>1), kb = s&1): 32 cols x 128k = 4KB.
    // dest layout [hk2 0..3][brow 0..31][2x16B]; 4 loads/lane, linear dest.
    auto stageB = [&](int s, int slot) {
        const int jt = j0 + (s >> 1);
        const int kb = s & 1;
        const unsigned char* src = e + (size_t)(jt * 128 + wn * 32) * DCOLS + kb * 128;
#pragma unroll
        for (int i = 0; i < 4; ++i) {
            const int u = i * 64 + l;         // 0..255
            const int hk2 = u >> 6, brow = (u >> 1) & 31, half = u & 1;
            __builtin_amdgcn_global_load_lds(
                (const __attribute__((address_space(1))) void*)(src + brow * DCOLS + hk2 * 32 + half * 16),
                (__attribute__((address_space(3))) void*)(myB + slot * 4096 + u * 16), 16, 0, 0);
        }
    };
    // stage A bounce for kb: 64 rows x 128k = 8KB; [hk2][row 0..63][2x16B].
    auto stageA = [&](int kb) {
#pragma unroll
        for (int i = 0; i < 2; ++i) {
            const int u = i * 256 + t;        // 0..511
            const int hk2 = u >> 7, arow = (u >> 1) & 63, half = u & 1;
            __builtin_amdgcn_global_load_lds(
                (const __attribute__((address_space(1))) void*)(eA + arow * DCOLS + kb * 128 + hk2 * 32 + half * 16),
                (__attribute__((address_space(3))) void*)(As + u * 16), 16, 0, 0);
        }
    };

    // --- prologue ---
    stageA(0);                                // 2 loads
    stageB(0, 0);                             // 4
    stageB(1, 1);                             // 4 -> 10 outstanding
    asm volatile("s_waitcnt vmcnt(8)" ::: "memory");   // A0 landed
    __builtin_amdgcn_s_barrier();
    __builtin_amdgcn_sched_barrier(0);

    i32x8 af[2][4];
#pragma unroll
    for (int m = 0; m < 4; ++m)
        af[0][m] = *reinterpret_cast<const i32x8*>(As + hk * 2048 + (m * 16 + lr) * 32);
    __builtin_amdgcn_s_barrier();             // all waves read A0
    __builtin_amdgcn_sched_barrier(0);
    stageA(1);
    asm volatile("s_waitcnt vmcnt(0)" ::: "memory");   // prologue-only drain
    __builtin_amdgcn_s_barrier();
    __builtin_amdgcn_sched_barrier(0);
#pragma unroll
    for (int m = 0; m < 4; ++m)
        af[1][m] = *reinterpret_cast<const i32x8*>(As + hk * 2048 + (m * 16 + lr) * 32);
    // A bounce now dead (red[] reuses it after final syncthreads).

    f32x4 acc[4][2];
#pragma unroll
    for (int m = 0; m < 4; ++m)
#pragma unroll
        for (int n = 0; n < 2; ++n)
            acc[m][n] = (f32x4){0.f, 0.f, 0.f, 0.f};

    float local = 0.0f;
    for (int jx = 0; jx < nj; ++jx) {
        const int jt = j0 + jx;
#pragma unroll
        for (int kb = 0; kb < 2; ++kb) {
            const int s = jx * 2 + kb;
            // gate: own stream s landed (<=4 outstanding = only s+1's stage)
            asm volatile("s_waitcnt vmcnt(4)" ::: "memory");
            i32x8 bf[2];
#pragma unroll
            for (int n = 0; n < 2; ++n)
                bf[n] = *reinterpret_cast<const i32x8*>(
                    myB + (s & 1) * 4096 + hk * 1024 + (n * 16 + lr) * 32);
            // order: reads complete before re-staging the same slot
            asm volatile("s_waitcnt lgkmcnt(0)" ::: "memory");
            __builtin_amdgcn_sched_barrier(0);
            if (s + 2 < NS) stageB(s + 2, s & 1);
            __builtin_amdgcn_s_setprio(1);
#pragma unroll
            for (int m = 0; m < 4; ++m)
#pragma unroll
                for (int n = 0; n < 2; ++n)
                    acc[m][n] = __builtin_amdgcn_mfma_scale_f32_16x16x128_f8f6f4(
                        af[kb][m], bf[n], acc[m][n],
                        1, 1,                 // cbsz=BF8(e5m2), blgp=BF8
                        0, 0x7F7F7F7F,        // scale A = 1.0
                        0, 0x7F7F7F7F);       // scale B = 1.0
            __builtin_amdgcn_s_setprio(0);
        }
        // --- tile jt complete: fused masked-relu reduce, reset acc ---
        // C/D layout (m89-verified; shape-determined): col=lane&15,
        // row=(lane>>4)*4+reg.
        const int gi0 = bi * 64;
        const int gj0 = jt * 128 + wn * 32;
        if (jt == (bi >> 1)) {                // diagonal-containing tile: mask
#pragma unroll
            for (int m = 0; m < 4; ++m)
#pragma unroll
                for (int n = 0; n < 2; ++n) {
#pragma unroll
                    for (int r2 = 0; r2 < 4; ++r2) {
                        const int gi = gi0 + m * 16 + hk * 4 + r2;
                        const int gj = gj0 + n * 16 + lr;
                        local += (gi < gj) ? fmaxf(acc[m][n][r2] - MARGIN, 0.0f) : 0.0f;
                    }
                    acc[m][n] = (f32x4){0.f, 0.f, 0.f, 0.f};
                }
        } else {                              // jt > bi/2: fully upper-tri
#pragma unroll
            for (int m = 0; m < 4; ++m)
#pragma unroll
                for (int n = 0; n < 2; ++n) {
#pragma unroll
                    for (int r2 = 0; r2 < 4; ++r2)
                        local += fmaxf(acc[m][n][r2] - MARGIN, 0.0f);
                    acc[m][n] = (f32x4){0.f, 0.f, 0.f, 0.f};
                }
        }
    }

    // --- block reduction -> one partial per block, no atomics ---
#pragma unroll
    for (int off = 32; off >= 1; off >>= 1) local += __shfl_down(local, off);
    __syncthreads();                          // all loop LDS traffic done
    float* red = (float*)lds;                 // reuse dead A bounce
    if (l == 0) red[w] = local;
    __syncthreads();
    if (t == 0) part[orig] = red[0] + red[1] + red[2] + red[3];
}

// --- Kernel 3: reduce NBLOCKS=1088 partials, finalize ---
__global__ __launch_bounds__(256) void fin_kernel(const float* __restrict__ part,
                                                  float* __restrict__ out) {
    __shared__ float red[4];
    const int t = threadIdx.x;
    float v = part[t] + part[t + 256] + part[t + 512] + part[t + 768]
            + (t < NBLOCKS - 1024 ? part[t + 1024] : 0.0f);
#pragma unroll
    for (int off = 32; off >= 1; off >>= 1) v += __shfl_down(v, off);
    if ((t & 63) == 0) red[t >> 6] = v;
    __syncthreads();
    if (t == 0) out[0] = (red[0] + red[1] + red[2] + red[3]) / 33550336.0f;
}

extern "C" void kernel_launch(void* const* d_in, const int* in_sizes, int n_in,
                              void* d_out, int out_size, void* d_ws, size_t ws_size,
                              hipStream_t stream) {
    const float* x = (const float*)d_in[0];
    float* out = (float*)d_out;
    unsigned char* e = (unsigned char*)d_ws;                        // 2 MB fp8
    float* part = (float*)((char*)d_ws + (size_t)NROWS * DCOLS);    // 1088 floats

    norm_kernel<<<NROWS / 8, 256, 0, stream>>>(x, e);
    tile_kernel<<<NBLOCKS, 256, 0, stream>>>(e, part);
    fin_kernel<<<1, 256, 0, stream>>>(part, out);
}